// Round 1
// baseline (121.799 us; speedup 1.0000x reference)
//
#include <hip/hip_runtime.h>

// Chamfer distance, B=16, N=M=4096, D=3.
// Strategy: dist(i,j) = n1 + n2 - 2*x1.x2 computed as ONE bf16 MFMA per 32x32
// tile with the norm terms folded into padded K slots; coordinates split into
// bf16 hi+lo pairs for ~fp32 accuracy. Row-mins accumulate in registers; the
// kernel runs twice (blockIdx.z) with P/Q swapped to get both directions
// without cross-block reductions. Per-wave sum-of-mins -> atomicAdd to out[b].

typedef __attribute__((ext_vector_type(8))) __bf16 bf16x8;
typedef __attribute__((ext_vector_type(16))) float f32x16;

#define TI 128       // rows per block (4 waves x 32)
#define JCHUNK 1024  // cols staged in LDS per chunk
#define THREADS 256

__device__ __forceinline__ unsigned f2bf(float f) {
  unsigned u = __float_as_uint(f);
  return (u + 0x7FFFu + ((u >> 16) & 1u)) >> 16;  // RNE bf16 bits (low 16)
}
__device__ __forceinline__ float bf2f(unsigned s) {
  return __uint_as_float(s << 16);
}
__device__ __forceinline__ unsigned pk(unsigned lo, unsigned hi) {
  return (lo & 0xFFFFu) | (hi << 16);
}

__global__ __launch_bounds__(THREADS, 4) void chamfer_mfma(
    const float* __restrict__ x1, const float* __restrict__ x2,
    float* __restrict__ out, int N, int M) {
  // k-vector layout (16 bf16 per row/col, 32B):
  // A (P side, row i):  [h x,y,z | h x,y,z | l x,y,z | 1 1 n1h n1l 0 0 0]
  // B (Q side, col j):  [H x,y,z | L x,y,z | H x,y,z | n2h n2l 1 1 0 0 0]
  //   where h,l split x1;  H,L split (-2*x2);  acc = n1 + n2 - 2*dot = dist.
  __shared__ __align__(16) unsigned short Al[TI * 16];      // 4 KB
  __shared__ __align__(16) unsigned short Ql[JCHUNK * 16];  // 32 KB

  const int b   = blockIdx.y;
  const int dir = blockIdx.z;
  const float* __restrict__ P = dir ? x2 : x1;
  const float* __restrict__ Q = dir ? x1 : x2;
  const int nrows = dir ? M : N;
  const int ncols = dir ? N : M;
  if ((int)blockIdx.x * TI >= nrows) return;

  const int tid = threadIdx.x;

  // ---- stage A-side k-vectors (once per block) ----
  if (tid < TI) {
    const int i = blockIdx.x * TI + tid;
    const float* p = P + (b * nrows + i) * 3;
    const float x = p[0], y = p[1], z = p[2];
    const unsigned hx = f2bf(x), hy = f2bf(y), hz = f2bf(z);
    const unsigned lx = f2bf(x - bf2f(hx));
    const unsigned ly = f2bf(y - bf2f(hy));
    const unsigned lz = f2bf(z - bf2f(hz));
    const float n = fmaf(x, x, fmaf(y, y, z * z));
    const unsigned nh = f2bf(n), nl = f2bf(n - bf2f(nh));
    const unsigned one = 0x3F80u;
    uint4 w0, w1;
    w0.x = pk(hx, hy); w0.y = pk(hz, hx); w0.z = pk(hy, hz); w0.w = pk(lx, ly);
    w1.x = pk(lz, one); w1.y = pk(one, nh); w1.z = pk(nl, 0u); w1.w = 0u;
    uint4* dst = (uint4*)&Al[tid * 16];
    dst[0] = w0; dst[1] = w1;
  }
  __syncthreads();

  const int lane = tid & 63;
  const int half = lane >> 5;   // which K-half this lane supplies
  const int l31  = lane & 31;
  const int wave = tid >> 6;

  const bf16x8 afrag = *(const bf16x8*)&Al[(wave * 32 + l31) * 16 + half * 8];

  f32x16 zero;
#pragma unroll
  for (int e = 0; e < 16; ++e) zero[e] = 0.f;

  float rowmin[16];
#pragma unroll
  for (int e = 0; e < 16; ++e) rowmin[e] = 3.0e38f;

  const int nchunk = ncols / JCHUNK;
  for (int c = 0; c < nchunk; ++c) {
    __syncthreads();  // previous chunk fully consumed
    // ---- stage Q-side k-vectors for this chunk (4 cols/thread) ----
#pragma unroll
    for (int s0 = 0; s0 < JCHUNK / THREADS; ++s0) {
      const int s = s0 * THREADS + tid;
      const int j = c * JCHUNK + s;
      const float* q = Q + (b * ncols + j) * 3;
      const float x = q[0], y = q[1], z = q[2];
      const float sx = -2.f * x, sy = -2.f * y, sz = -2.f * z;
      const unsigned Hx = f2bf(sx), Hy = f2bf(sy), Hz = f2bf(sz);
      const unsigned Lx = f2bf(sx - bf2f(Hx));
      const unsigned Ly = f2bf(sy - bf2f(Hy));
      const unsigned Lz = f2bf(sz - bf2f(Hz));
      const float n = fmaf(x, x, fmaf(y, y, z * z));
      const unsigned nh = f2bf(n), nl = f2bf(n - bf2f(nh));
      const unsigned one = 0x3F80u;
      uint4 w0, w1;
      w0.x = pk(Hx, Hy); w0.y = pk(Hz, Lx); w0.z = pk(Ly, Lz); w0.w = pk(Hx, Hy);
      w1.x = pk(Hz, nh); w1.y = pk(nl, one); w1.z = pk(one, 0u); w1.w = 0u;
      uint4* dst = (uint4*)&Ql[s * 16];
      dst[0] = w0; dst[1] = w1;
    }
    __syncthreads();

    // ---- 32 MFMA tiles over this chunk; running row-min in registers ----
#pragma unroll
    for (int jt = 0; jt < JCHUNK / 32; ++jt) {
      const bf16x8 bfrag =
          *(const bf16x8*)&Ql[(jt * 32 + l31) * 16 + half * 8];
      const f32x16 acc =
          __builtin_amdgcn_mfma_f32_32x32x16_bf16(afrag, bfrag, zero, 0, 0, 0);
#pragma unroll
      for (int e = 0; e < 16; ++e) rowmin[e] = fminf(rowmin[e], acc[e]);
    }
  }

  // ---- epilogue: full row mins (butterfly over 32 cols), sum, atomicAdd ----
  float ssum = 0.f;
#pragma unroll
  for (int e = 0; e < 16; ++e) {
    float v = rowmin[e];
    v = fminf(v, __shfl_xor(v, 1));
    v = fminf(v, __shfl_xor(v, 2));
    v = fminf(v, __shfl_xor(v, 4));
    v = fminf(v, __shfl_xor(v, 8));
    v = fminf(v, __shfl_xor(v, 16));
    ssum += v;  // each reg e is a distinct row of this half
  }
  ssum += __shfl_xor(ssum, 32);  // combine the two 16-row halves
  if (lane == 0) atomicAdd(&out[b], ssum * (1.0f / (float)nrows));
}

extern "C" void kernel_launch(void* const* d_in, const int* in_sizes, int n_in,
                              void* d_out, int out_size, void* d_ws,
                              size_t ws_size, hipStream_t stream) {
  const float* x1 = (const float*)d_in[0];
  const float* x2 = (const float*)d_in[1];
  float* out = (float*)d_out;
  const int B = out_size;                // 16
  const int N = in_sizes[0] / (3 * B);   // 4096
  const int M = in_sizes[1] / (3 * B);   // 4096

  hipMemsetAsync(out, 0, B * sizeof(float), stream);  // capture-safe
  dim3 grid(N / TI, B, 2);
  chamfer_mfma<<<grid, THREADS, 0, stream>>>(x1, x2, out, N, M);
}

// Round 2
// 98.105 us; speedup vs baseline: 1.2415x; 1.2415x over previous
//
#include <hip/hip_runtime.h>

// Chamfer distance, B=16, N=M=4096, D=3.
// dist(i,j) = n1 + n2 - 2*x1.x2 as ONE bf16 MFMA per 32x32 tile: norm terms
// folded into padded K slots, coords split into bf16 hi+lo for fp32-grade
// accuracy (R1: absmax 0.0). Row-mins in registers; kernel runs both
// directions via blockIdx.z. R2 changes: conflict-free [jtile][half][col]
// LDS layout (R1 had ~8-way conflicts on ds_read_b128), 2 row-tiles per wave
// (halves LDS reads per MFMA, 2x MFMA ILP), v_min3 pairing over j-tiles.

typedef __attribute__((ext_vector_type(8))) __bf16 bf16x8;
typedef __attribute__((ext_vector_type(16))) float f32x16;

#define TI 256       // rows per block (4 waves x 64 rows)
#define JCHUNK 1024  // cols staged in LDS per chunk
#define THREADS 256

__device__ __forceinline__ unsigned f2bf(float f) {
  unsigned u = __float_as_uint(f);
  return (u + 0x7FFFu + ((u >> 16) & 1u)) >> 16;  // RNE bf16 bits (low 16)
}
__device__ __forceinline__ float bf2f(unsigned s) {
  return __uint_as_float(s << 16);
}
__device__ __forceinline__ unsigned pk(unsigned lo, unsigned hi) {
  return (lo & 0xFFFFu) | (hi << 16);
}

__global__ __launch_bounds__(THREADS, 4) void chamfer_mfma(
    const float* __restrict__ x1, const float* __restrict__ x2,
    float* __restrict__ out, int N, int M) {
  // k-vector layout (16 bf16 = two uint4 halves w0/w1):
  // A (P side, row i):  w0=[hx hy hz hx hy hz lx ly]  w1=[lz 1 1 nh nl 0 0 0]
  // B (Q side, col j):  w0=[Hx Hy Hz Lx Ly Lz Hx Hy]  w1=[Hz nh nl 1 1 0 0 0]
  //   h,l split x1;  H,L split (-2*x2);  acc = n1 + n2 - 2*dot = dist.
  // Storage: frag halves as 16B units, [tile][half][lane31] so a wave64 read
  // (lane = half*32+c) is a contiguous 1 KB line -> zero bank conflicts.
  __shared__ uint4 Al4[(TI / 32) * 2 * 32];      //  8 KB
  __shared__ uint4 Ql4[(JCHUNK / 32) * 2 * 32];  // 32 KB

  const int b   = blockIdx.y;
  const int dir = blockIdx.z;
  const float* __restrict__ P = dir ? x2 : x1;
  const float* __restrict__ Q = dir ? x1 : x2;
  const int nrows = dir ? M : N;
  const int ncols = dir ? N : M;

  const int tid = threadIdx.x;

  // ---- stage A-side k-vectors (one row per thread, once per block) ----
  {
    const int i = blockIdx.x * TI + tid;
    const float* p = P + (b * nrows + i) * 3;
    const float x = p[0], y = p[1], z = p[2];
    const unsigned hx = f2bf(x), hy = f2bf(y), hz = f2bf(z);
    const unsigned lx = f2bf(x - bf2f(hx));
    const unsigned ly = f2bf(y - bf2f(hy));
    const unsigned lz = f2bf(z - bf2f(hz));
    const float n = fmaf(x, x, fmaf(y, y, z * z));
    const unsigned nh = f2bf(n), nl = f2bf(n - bf2f(nh));
    const unsigned one = 0x3F80u;
    uint4 w0, w1;
    w0.x = pk(hx, hy); w0.y = pk(hz, hx); w0.z = pk(hy, hz); w0.w = pk(lx, ly);
    w1.x = pk(lz, one); w1.y = pk(one, nh); w1.z = pk(nl, 0u); w1.w = 0u;
    Al4[((tid >> 5) * 2 + 0) * 32 + (tid & 31)] = w0;
    Al4[((tid >> 5) * 2 + 1) * 32 + (tid & 31)] = w1;
  }
  __syncthreads();

  const int lane = tid & 63;
  const int half = lane >> 5;  // which K-half this lane supplies to MFMA
  const int l31  = lane & 31;
  const int wave = tid >> 6;   // wave owns rows [wave*64, wave*64+64)

  const bf16x8 af0 = *(const bf16x8*)&Al4[(wave * 4 + 0 + half) * 32 + l31];
  const bf16x8 af1 = *(const bf16x8*)&Al4[(wave * 4 + 2 + half) * 32 + l31];

  f32x16 zero;
#pragma unroll
  for (int e = 0; e < 16; ++e) zero[e] = 0.f;

  float rm0[16], rm1[16];
#pragma unroll
  for (int e = 0; e < 16; ++e) { rm0[e] = 3.0e38f; rm1[e] = 3.0e38f; }

  const int nchunk = ncols / JCHUNK;
  for (int c = 0; c < nchunk; ++c) {
    __syncthreads();  // previous chunk fully consumed
    // ---- stage Q-side k-vectors for this chunk (4 cols/thread) ----
#pragma unroll
    for (int s0 = 0; s0 < JCHUNK / THREADS; ++s0) {
      const int s = s0 * THREADS + tid;
      const int j = c * JCHUNK + s;
      const float* q = Q + (b * ncols + j) * 3;
      const float x = q[0], y = q[1], z = q[2];
      const float sx = -2.f * x, sy = -2.f * y, sz = -2.f * z;
      const unsigned Hx = f2bf(sx), Hy = f2bf(sy), Hz = f2bf(sz);
      const unsigned Lx = f2bf(sx - bf2f(Hx));
      const unsigned Ly = f2bf(sy - bf2f(Hy));
      const unsigned Lz = f2bf(sz - bf2f(Hz));
      const float n = fmaf(x, x, fmaf(y, y, z * z));
      const unsigned nh = f2bf(n), nl = f2bf(n - bf2f(nh));
      const unsigned one = 0x3F80u;
      uint4 w0, w1;
      w0.x = pk(Hx, Hy); w0.y = pk(Hz, Lx); w0.z = pk(Ly, Lz); w0.w = pk(Hx, Hy);
      w1.x = pk(Hz, nh); w1.y = pk(nl, one); w1.z = pk(one, 0u); w1.w = 0u;
      Ql4[(s >> 5) * 64 + (s & 31)] = w0;
      Ql4[(s >> 5) * 64 + 32 + (s & 31)] = w1;
    }
    __syncthreads();

    // ---- 32 j-tiles: 2 per iter, 4 MFMAs, fold with v_min3 ----
#pragma unroll 4
    for (int jt = 0; jt < JCHUNK / 32; jt += 2) {
      const bf16x8 b0 = *(const bf16x8*)&Ql4[jt * 64 + half * 32 + l31];
      const bf16x8 b1 = *(const bf16x8*)&Ql4[(jt + 1) * 64 + half * 32 + l31];
      const f32x16 a00 =
          __builtin_amdgcn_mfma_f32_32x32x16_bf16(af0, b0, zero, 0, 0, 0);
      const f32x16 a01 =
          __builtin_amdgcn_mfma_f32_32x32x16_bf16(af0, b1, zero, 0, 0, 0);
#pragma unroll
      for (int e = 0; e < 16; ++e)
        rm0[e] = fminf(fminf(a00[e], a01[e]), rm0[e]);  // v_min3_f32
      const f32x16 a10 =
          __builtin_amdgcn_mfma_f32_32x32x16_bf16(af1, b0, zero, 0, 0, 0);
      const f32x16 a11 =
          __builtin_amdgcn_mfma_f32_32x32x16_bf16(af1, b1, zero, 0, 0, 0);
#pragma unroll
      for (int e = 0; e < 16; ++e)
        rm1[e] = fminf(fminf(a10[e], a11[e]), rm1[e]);
    }
  }

  // ---- epilogue: butterfly row-min over the 32 cols held per lane-half ----
  float ssum = 0.f;
#pragma unroll
  for (int e = 0; e < 16; ++e) {
    float v = rm0[e];
    v = fminf(v, __shfl_xor(v, 1));
    v = fminf(v, __shfl_xor(v, 2));
    v = fminf(v, __shfl_xor(v, 4));
    v = fminf(v, __shfl_xor(v, 8));
    v = fminf(v, __shfl_xor(v, 16));
    ssum += v;
  }
#pragma unroll
  for (int e = 0; e < 16; ++e) {
    float v = rm1[e];
    v = fminf(v, __shfl_xor(v, 1));
    v = fminf(v, __shfl_xor(v, 2));
    v = fminf(v, __shfl_xor(v, 4));
    v = fminf(v, __shfl_xor(v, 8));
    v = fminf(v, __shfl_xor(v, 16));
    ssum += v;
  }
  ssum += __shfl_xor(ssum, 32);  // combine the two 16-row lane halves
  if (lane == 0) atomicAdd(&out[b], ssum * (1.0f / (float)nrows));
}

extern "C" void kernel_launch(void* const* d_in, const int* in_sizes, int n_in,
                              void* d_out, int out_size, void* d_ws,
                              size_t ws_size, hipStream_t stream) {
  const float* x1 = (const float*)d_in[0];
  const float* x2 = (const float*)d_in[1];
  float* out = (float*)d_out;
  const int B = out_size;               // 16
  const int N = in_sizes[0] / (3 * B);  // 4096
  const int M = in_sizes[1] / (3 * B);  // 4096

  hipMemsetAsync(out, 0, B * sizeof(float), stream);  // capture-safe
  dim3 grid(N / TI, B, 2);
  chamfer_mfma<<<grid, THREADS, 0, stream>>>(x1, x2, out, N, M);
}

// Round 3
// 92.615 us; speedup vs baseline: 1.3151x; 1.0593x over previous
//
#include <hip/hip_runtime.h>

// Chamfer distance, B=16, N=M=4096, D=3.
// dist(i,j) = n1 + n2 - 2*x1.x2 as ONE bf16 MFMA per 32x32 tile (norms folded
// into padded K slots, hi/lo bf16 split => fp32-grade accuracy; R1/R2 absmax 0).
// R3: latency-bound fix. Main kernel has NO LDS and NO barriers: B-side MFMA
// fragments are prepacked to d_ws by a helper kernel and streamed global->VGPR
// (16B/lane coalesced, L2-resident); A-frags built per-lane from raw points.
// Column range split x2 => 4096 waves; per-row mins combined via uint atomicMin
// (distances >= 0 so float bit-pattern order == float order); tiny reduce kernel
// produces out[b].

typedef __attribute__((ext_vector_type(8))) __bf16 bf16x8;
typedef __attribute__((ext_vector_type(16))) float f32x16;

#define PTS 4096
#define TILES 128  // PTS/32
#define NB 16

__device__ __forceinline__ unsigned f2bf(float f) {
  unsigned u = __float_as_uint(f);
  return (u + 0x7FFFu + ((u >> 16) & 1u)) >> 16;  // RNE bf16 bits
}
__device__ __forceinline__ float bf2f(unsigned s) {
  return __uint_as_float(s << 16);
}
__device__ __forceinline__ unsigned pk(unsigned lo, unsigned hi) {
  return (lo & 0xFFFFu) | (hi << 16);
}

// ---- prepack B-side fragments: Bfr[(((d*NB+b)*TILES+t)*2+h)*32 + l31] ----
// B k-vec: w0=[Hx Hy Hz Lx Ly Lz Hx Hy]  w1=[Hz nh nl 1 1 0 0 0],  H,L split -2*q.
__global__ __launch_bounds__(256) void prepack_b(const float* __restrict__ x1,
                                                 const float* __restrict__ x2,
                                                 uint4* __restrict__ Bfr) {
  const int id = blockIdx.x * 256 + threadIdx.x;  // 2*NB*PTS = 131072
  const int d = id >> 16;
  const int b = (id >> 12) & (NB - 1);
  const int j = id & (PTS - 1);
  const float* q = (d ? x1 : x2) + (size_t)(b * PTS + j) * 3;
  const float x = q[0], y = q[1], z = q[2];
  const float sx = -2.f * x, sy = -2.f * y, sz = -2.f * z;
  const unsigned Hx = f2bf(sx), Hy = f2bf(sy), Hz = f2bf(sz);
  const unsigned Lx = f2bf(sx - bf2f(Hx));
  const unsigned Ly = f2bf(sy - bf2f(Hy));
  const unsigned Lz = f2bf(sz - bf2f(Hz));
  const float n = fmaf(x, x, fmaf(y, y, z * z));
  const unsigned nh = f2bf(n), nl = f2bf(n - bf2f(nh));
  const unsigned one = 0x3F80u;
  uint4 w0, w1;
  w0.x = pk(Hx, Hy); w0.y = pk(Hz, Lx); w0.z = pk(Ly, Lz); w0.w = pk(Hx, Hy);
  w1.x = pk(Hz, nh); w1.y = pk(nl, one); w1.z = pk(one, 0u); w1.w = 0u;
  uint4* base =
      Bfr + ((size_t)((d * NB + b) * TILES + (j >> 5)) * 2) * 32 + (j & 31);
  base[0]  = w0;   // half 0
  base[32] = w1;   // half 1
}

// ---- main: 128 threads (2 waves), wave = 64 rows x 2048 cols, no LDS/barriers
__global__ __launch_bounds__(128, 3) void chamfer_main(
    const float* __restrict__ x1, const float* __restrict__ x2,
    const uint4* __restrict__ Bfr, unsigned* __restrict__ rowm) {
  const int rb = blockIdx.x;       // 32 row-blocks of 128 rows
  const int b  = blockIdx.y;       // batch
  const int z  = blockIdx.z;       // dir*2 + colhalf
  const int d  = z >> 1, ch = z & 1;

  const int tid  = threadIdx.x;
  const int lane = tid & 63;
  const int half = lane >> 5;      // K-half this lane supplies to MFMA
  const int l31  = lane & 31;
  const int wave = tid >> 6;

  // --- build A fragments from raw points (rows t*32+l31, t = t0, t0+1) ---
  // A k-vec: w0=[hx hy hz hx hy hz lx ly]  w1=[lz 1 1 nh nl 0 0 0]
  const float* P = d ? x2 : x1;
  const int t0 = rb * 4 + wave * 2;
  bf16x8 af[2];
#pragma unroll
  for (int rr = 0; rr < 2; ++rr) {
    const int r = (t0 + rr) * 32 + l31;
    const float* p = P + (size_t)(b * PTS + r) * 3;
    const float x = p[0], y = p[1], zc = p[2];
    const unsigned hx = f2bf(x), hy = f2bf(y), hz = f2bf(zc);
    const unsigned lx = f2bf(x - bf2f(hx));
    const unsigned ly = f2bf(y - bf2f(hy));
    const unsigned lz = f2bf(zc - bf2f(hz));
    const float n = fmaf(x, x, fmaf(y, y, zc * zc));
    const unsigned nh = f2bf(n), nl = f2bf(n - bf2f(nh));
    const unsigned one = 0x3F80u;
    uint4 w0, w1;
    w0.x = pk(hx, hy); w0.y = pk(hz, hx); w0.z = pk(hy, hz); w0.w = pk(lx, ly);
    w1.x = pk(lz, one); w1.y = pk(one, nh); w1.z = pk(nl, 0u); w1.w = 0u;
    uint4 w;
    w.x = half ? w1.x : w0.x; w.y = half ? w1.y : w0.y;
    w.z = half ? w1.z : w0.z; w.w = half ? w1.w : w0.w;
    af[rr] = *(const bf16x8*)&w;
  }
  const bf16x8 af0 = af[0], af1 = af[1];

  f32x16 zero;
#pragma unroll
  for (int e = 0; e < 16; ++e) zero[e] = 0.f;

  float rm0[16], rm1[16];
#pragma unroll
  for (int e = 0; e < 16; ++e) { rm0[e] = 3.0e38f; rm1[e] = 3.0e38f; }

  // --- stream 64 j-tiles (this col-half) straight from global (L2) ---
  const uint4* bp =
      Bfr + ((size_t)((d * NB + b) * TILES + ch * 64) * 2) * 32;
  const int off = half * 32 + l31;  // within a tile: h*32 + col
  bf16x8 b0 = *(const bf16x8*)&bp[off];
  bf16x8 b1 = *(const bf16x8*)&bp[64 + off];
#pragma unroll 2
  for (int jt = 0; jt < 64; jt += 2) {
    const int nx = (jt + 2) & 63;  // wrap: last-iter prefetch is redundant, safe
    const bf16x8 n0 = *(const bf16x8*)&bp[nx * 64 + off];
    const bf16x8 n1 = *(const bf16x8*)&bp[(nx + 1) * 64 + off];
    const f32x16 a00 =
        __builtin_amdgcn_mfma_f32_32x32x16_bf16(af0, b0, zero, 0, 0, 0);
    const f32x16 a01 =
        __builtin_amdgcn_mfma_f32_32x32x16_bf16(af0, b1, zero, 0, 0, 0);
#pragma unroll
    for (int e = 0; e < 16; ++e)
      rm0[e] = fminf(fminf(a00[e], a01[e]), rm0[e]);  // v_min3_f32
    const f32x16 a10 =
        __builtin_amdgcn_mfma_f32_32x32x16_bf16(af1, b0, zero, 0, 0, 0);
    const f32x16 a11 =
        __builtin_amdgcn_mfma_f32_32x32x16_bf16(af1, b1, zero, 0, 0, 0);
#pragma unroll
    for (int e = 0; e < 16; ++e)
      rm1[e] = fminf(fminf(a10[e], a11[e]), rm1[e]);
    b0 = n0; b1 = n1;
  }

  // --- per-row min over this wave's 32 cols-per-half, then uint atomicMin ---
  // C/D layout: col = lane&31, row_local = (e&3) + 8*(e>>2) + 4*half.
  unsigned* rbase = rowm + (size_t)(d * NB + b) * PTS + rb * 128 + wave * 64;
#pragma unroll
  for (int e = 0; e < 16; ++e) {
    float v = rm0[e];
    v = fminf(v, __shfl_xor(v, 1));
    v = fminf(v, __shfl_xor(v, 2));
    v = fminf(v, __shfl_xor(v, 4));
    v = fminf(v, __shfl_xor(v, 8));
    v = fminf(v, __shfl_xor(v, 16));
    if (l31 == e) {
      const int rl = (e & 3) + 8 * (e >> 2) + 4 * half;
      atomicMin(rbase + rl, __float_as_uint(fmaxf(v, 0.f)));
    }
  }
#pragma unroll
  for (int e = 0; e < 16; ++e) {
    float v = rm1[e];
    v = fminf(v, __shfl_xor(v, 1));
    v = fminf(v, __shfl_xor(v, 2));
    v = fminf(v, __shfl_xor(v, 4));
    v = fminf(v, __shfl_xor(v, 8));
    v = fminf(v, __shfl_xor(v, 16));
    if (l31 == e) {
      const int rl = 32 + (e & 3) + 8 * (e >> 2) + 4 * half;
      atomicMin(rbase + rl, __float_as_uint(fmaxf(v, 0.f)));
    }
  }
}

// ---- reduce: out[b] = mean(rowmin d=0) + mean(rowmin d=1) ----
__global__ __launch_bounds__(256) void reduce_rows(
    const unsigned* __restrict__ rowm, float* __restrict__ out) {
  const int b = blockIdx.x;
  const int tid = threadIdx.x;
  const unsigned* r0 = rowm + (size_t)b * PTS;
  const unsigned* r1 = rowm + (size_t)(NB + b) * PTS;
  float s = 0.f;
  for (int i = tid; i < PTS; i += 256)
    s += __uint_as_float(r0[i]) + __uint_as_float(r1[i]);
  s += __shfl_xor(s, 1);
  s += __shfl_xor(s, 2);
  s += __shfl_xor(s, 4);
  s += __shfl_xor(s, 8);
  s += __shfl_xor(s, 16);
  s += __shfl_xor(s, 32);
  __shared__ float acc[4];
  if ((tid & 63) == 0) acc[tid >> 6] = s;
  __syncthreads();
  if (tid == 0) out[b] = (acc[0] + acc[1] + acc[2] + acc[3]) * (1.f / PTS);
}

extern "C" void kernel_launch(void* const* d_in, const int* in_sizes, int n_in,
                              void* d_out, int out_size, void* d_ws,
                              size_t ws_size, hipStream_t stream) {
  const float* x1 = (const float*)d_in[0];
  const float* x2 = (const float*)d_in[1];
  float* out = (float*)d_out;

  uint4* Bfr = (uint4*)d_ws;  // 2*NB*TILES*2*32 uint4 = 4 MB
  unsigned* rowm = (unsigned*)((char*)d_ws + (size_t)2 * NB * TILES * 2 * 32 * 16);
  hipMemsetAsync(rowm, 0xFF, (size_t)2 * NB * PTS * 4, stream);  // +inf as uint

  prepack_b<<<(2 * NB * PTS) / 256, 256, 0, stream>>>(x1, x2, Bfr);
  dim3 grid(PTS / 128, NB, 4);  // rowblock, batch, dir*2+colhalf
  chamfer_main<<<grid, 128, 0, stream>>>(x1, x2, Bfr, rowm);
  reduce_rows<<<NB, 256, 0, stream>>>(rowm, out);
}

// Round 4
// 88.186 us; speedup vs baseline: 1.3812x; 1.0502x over previous
//
#include <hip/hip_runtime.h>

// Chamfer distance, B=16, N=M=4096, D=3.
// dist(i,j) = n1 + n2 - 2*x1.x2 as ONE bf16 MFMA per 32x32 tile (norms folded
// into padded K slots, hi/lo bf16 split => exact-grade; absmax 0.0 since R1).
// R4 (MLP fix; R3 was ~8x short on loads-in-flight by Little's law):
//  - block = 4 waves over 256 rows sharing the IDENTICAL col stream -> L1 reuse
//  - explicit 8-slot prefetch ring (groups of 4 tiles, double-buffered)
//  - grid.x = 64 (dir,b,ch) slices -> XCD = slice%8 pins each slice's stream
//    to one XCD's L2
//  - prepack kernel also inits rowm (no memset dispatch)

typedef __attribute__((ext_vector_type(8))) __bf16 bf16x8;
typedef __attribute__((ext_vector_type(16))) float f32x16;

#define PTS 4096
#define TILES 128  // PTS/32
#define NB 16

__device__ __forceinline__ unsigned f2bf(float f) {
  unsigned u = __float_as_uint(f);
  return (u + 0x7FFFu + ((u >> 16) & 1u)) >> 16;  // RNE bf16 bits
}
__device__ __forceinline__ float bf2f(unsigned s) {
  return __uint_as_float(s << 16);
}
__device__ __forceinline__ unsigned pk(unsigned lo, unsigned hi) {
  return (lo & 0xFFFFu) | (hi << 16);
}

// ---- prepack B-side fragments + init rowm ----
// Bfr[(((d*NB+b)*TILES+t)*2+h)*32 + l31]
// B k-vec: w0=[Hx Hy Hz Lx Ly Lz Hx Hy]  w1=[Hz nh nl 1 1 0 0 0], H,L split -2q.
__global__ __launch_bounds__(256) void prepack_b(const float* __restrict__ x1,
                                                 const float* __restrict__ x2,
                                                 uint4* __restrict__ Bfr,
                                                 unsigned* __restrict__ rowm) {
  const int id = blockIdx.x * 256 + threadIdx.x;  // 2*NB*PTS = 131072
  rowm[id] = 0x7F800000u;                         // +inf (all dists >= 0)
  const int d = id >> 16;
  const int b = (id >> 12) & (NB - 1);
  const int j = id & (PTS - 1);
  const float* q = (d ? x1 : x2) + (size_t)(b * PTS + j) * 3;
  const float x = q[0], y = q[1], z = q[2];
  const float sx = -2.f * x, sy = -2.f * y, sz = -2.f * z;
  const unsigned Hx = f2bf(sx), Hy = f2bf(sy), Hz = f2bf(sz);
  const unsigned Lx = f2bf(sx - bf2f(Hx));
  const unsigned Ly = f2bf(sy - bf2f(Hy));
  const unsigned Lz = f2bf(sz - bf2f(Hz));
  const float n = fmaf(x, x, fmaf(y, y, z * z));
  const unsigned nh = f2bf(n), nl = f2bf(n - bf2f(nh));
  const unsigned one = 0x3F80u;
  uint4 w0, w1;
  w0.x = pk(Hx, Hy); w0.y = pk(Hz, Lx); w0.z = pk(Ly, Lz); w0.w = pk(Hx, Hy);
  w1.x = pk(Hz, nh); w1.y = pk(nl, one); w1.z = pk(one, 0u); w1.w = 0u;
  uint4* base =
      Bfr + ((size_t)((d * NB + b) * TILES + (j >> 5)) * 2) * 32 + (j & 31);
  base[0]  = w0;   // half 0
  base[32] = w1;   // half 1
}

// ---- main: 256 threads (4 waves). All 4 waves stream the SAME 64 col-tiles
// (different rows) -> L1 temporal reuse. No LDS, no barriers.
__global__ __launch_bounds__(256, 4) void chamfer_main(
    const float* __restrict__ x1, const float* __restrict__ x2,
    const uint4* __restrict__ Bfr, unsigned* __restrict__ rowm) {
  const int s  = blockIdx.x;           // 64 slices: (dir, batch, colhalf)
  const int d  = s & 1;
  const int b  = (s >> 1) & (NB - 1);
  const int ch = (s >> 5) & 1;
  const int rg = blockIdx.y;           // 16 row-groups of 256 rows

  const int tid  = threadIdx.x;
  const int lane = tid & 63;
  const int half = lane >> 5;          // K-half this lane supplies to MFMA
  const int l31  = lane & 31;
  const int wave = tid >> 6;

  // --- build A fragments from raw points (row tiles t0, t0+1) ---
  // A k-vec: w0=[hx hy hz hx hy hz lx ly]  w1=[lz 1 1 nh nl 0 0 0]
  const float* P = d ? x2 : x1;
  const int t0 = rg * 8 + wave * 2;
  bf16x8 af[2];
#pragma unroll
  for (int rr = 0; rr < 2; ++rr) {
    const int r = (t0 + rr) * 32 + l31;
    const float* p = P + (size_t)(b * PTS + r) * 3;
    const float x = p[0], y = p[1], zc = p[2];
    const unsigned hx = f2bf(x), hy = f2bf(y), hz = f2bf(zc);
    const unsigned lx = f2bf(x - bf2f(hx));
    const unsigned ly = f2bf(y - bf2f(hy));
    const unsigned lz = f2bf(zc - bf2f(hz));
    const float n = fmaf(x, x, fmaf(y, y, zc * zc));
    const unsigned nh = f2bf(n), nl = f2bf(n - bf2f(nh));
    const unsigned one = 0x3F80u;
    uint4 w0, w1;
    w0.x = pk(hx, hy); w0.y = pk(hz, hx); w0.z = pk(hy, hz); w0.w = pk(lx, ly);
    w1.x = pk(lz, one); w1.y = pk(one, nh); w1.z = pk(nl, 0u); w1.w = 0u;
    uint4 w;
    w.x = half ? w1.x : w0.x; w.y = half ? w1.y : w0.y;
    w.z = half ? w1.z : w0.z; w.w = half ? w1.w : w0.w;
    af[rr] = *(const bf16x8*)&w;
  }
  const bf16x8 af0 = af[0], af1 = af[1];

  f32x16 zero;
#pragma unroll
  for (int e = 0; e < 16; ++e) zero[e] = 0.f;

  float rm0[16], rm1[16];
#pragma unroll
  for (int e = 0; e < 16; ++e) { rm0[e] = 3.0e38f; rm1[e] = 3.0e38f; }

  // --- stream this col-half's 64 tiles; 8-slot ring, 4 loads in flight ---
  const uint4* bp = Bfr + ((size_t)((d * NB + b) * TILES + ch * 64) * 2) * 32;
  const int off = half * 32 + l31;  // within a tile: h*32 + col
  bf16x8 buf[8];
#pragma unroll
  for (int t = 0; t < 4; ++t) buf[t] = *(const bf16x8*)&bp[t * 64 + off];

#pragma unroll 2
  for (int g = 0; g < 16; ++g) {
    const int cur = (g & 1) * 4;
    const int nxt = ((g + 1) & 1) * 4;
    const int pf  = ((g + 1) & 15) * 4;  // wrap: last prefetch redundant, safe
#pragma unroll
    for (int t = 0; t < 4; ++t)
      buf[nxt + t] = *(const bf16x8*)&bp[(pf + t) * 64 + off];
#pragma unroll
    for (int t = 0; t < 4; t += 2) {
      const bf16x8 b0 = buf[cur + t], b1 = buf[cur + t + 1];
      const f32x16 a00 =
          __builtin_amdgcn_mfma_f32_32x32x16_bf16(af0, b0, zero, 0, 0, 0);
      const f32x16 a01 =
          __builtin_amdgcn_mfma_f32_32x32x16_bf16(af0, b1, zero, 0, 0, 0);
#pragma unroll
      for (int e = 0; e < 16; ++e)
        rm0[e] = fminf(fminf(a00[e], a01[e]), rm0[e]);  // v_min3_f32
      const f32x16 a10 =
          __builtin_amdgcn_mfma_f32_32x32x16_bf16(af1, b0, zero, 0, 0, 0);
      const f32x16 a11 =
          __builtin_amdgcn_mfma_f32_32x32x16_bf16(af1, b1, zero, 0, 0, 0);
#pragma unroll
      for (int e = 0; e < 16; ++e)
        rm1[e] = fminf(fminf(a10[e], a11[e]), rm1[e]);
    }
  }

  // --- per-row min over this wave's 32 cols-per-half, then uint atomicMin ---
  // C/D layout: col = lane&31, row_local = (e&3) + 8*(e>>2) + 4*half.
  unsigned* rbase = rowm + (size_t)(d * NB + b) * PTS + t0 * 32;
#pragma unroll
  for (int e = 0; e < 16; ++e) {
    float v = rm0[e];
    v = fminf(v, __shfl_xor(v, 1));
    v = fminf(v, __shfl_xor(v, 2));
    v = fminf(v, __shfl_xor(v, 4));
    v = fminf(v, __shfl_xor(v, 8));
    v = fminf(v, __shfl_xor(v, 16));
    if (l31 == e) {
      const int rl = (e & 3) + 8 * (e >> 2) + 4 * half;
      atomicMin(rbase + rl, __float_as_uint(fmaxf(v, 0.f)));
    }
  }
#pragma unroll
  for (int e = 0; e < 16; ++e) {
    float v = rm1[e];
    v = fminf(v, __shfl_xor(v, 1));
    v = fminf(v, __shfl_xor(v, 2));
    v = fminf(v, __shfl_xor(v, 4));
    v = fminf(v, __shfl_xor(v, 8));
    v = fminf(v, __shfl_xor(v, 16));
    if (l31 == e) {
      const int rl = 32 + (e & 3) + 8 * (e >> 2) + 4 * half;
      atomicMin(rbase + rl, __float_as_uint(fmaxf(v, 0.f)));
    }
  }
}

// ---- reduce: out[b] = mean(rowmin d=0) + mean(rowmin d=1) ----
__global__ __launch_bounds__(256) void reduce_rows(
    const unsigned* __restrict__ rowm, float* __restrict__ out) {
  const int b = blockIdx.x;
  const int tid = threadIdx.x;
  const unsigned* r0 = rowm + (size_t)b * PTS;
  const unsigned* r1 = rowm + (size_t)(NB + b) * PTS;
  float s = 0.f;
  for (int i = tid; i < PTS; i += 256)
    s += __uint_as_float(r0[i]) + __uint_as_float(r1[i]);
  s += __shfl_xor(s, 1);
  s += __shfl_xor(s, 2);
  s += __shfl_xor(s, 4);
  s += __shfl_xor(s, 8);
  s += __shfl_xor(s, 16);
  s += __shfl_xor(s, 32);
  __shared__ float acc[4];
  if ((tid & 63) == 0) acc[tid >> 6] = s;
  __syncthreads();
  if (tid == 0) out[b] = (acc[0] + acc[1] + acc[2] + acc[3]) * (1.f / PTS);
}

extern "C" void kernel_launch(void* const* d_in, const int* in_sizes, int n_in,
                              void* d_out, int out_size, void* d_ws,
                              size_t ws_size, hipStream_t stream) {
  const float* x1 = (const float*)d_in[0];
  const float* x2 = (const float*)d_in[1];
  float* out = (float*)d_out;

  uint4* Bfr = (uint4*)d_ws;  // 2*NB*TILES*2*32 uint4 = 4 MB
  unsigned* rowm =
      (unsigned*)((char*)d_ws + (size_t)2 * NB * TILES * 2 * 32 * 16);

  prepack_b<<<(2 * NB * PTS) / 256, 256, 0, stream>>>(x1, x2, Bfr, rowm);
  dim3 grid(64, NB);  // x = (dir,b,ch) slice -> XCD = x%8 ; y = row-group
  chamfer_main<<<grid, 256, 0, stream>>>(x1, x2, Bfr, rowm);
  reduce_rows<<<NB, 256, 0, stream>>>(rowm, out);
}